// Round 2
// baseline (338.617 us; speedup 1.0000x reference)
//
#include <hip/hip_runtime.h>

#define G 16
#define N 40000
#define D 64      // z_dim; 16 float4 per node
#define HID 256
#define C 5

// k_sums geometry: NB blocks per g; each block = 800 nodes; each wave owns a
// contiguous 200-node span -> every wave-iter is an aligned 1 KB request.
#define NB 50
#define CHUNKS 800
#define WNODES 200            // CHUNKS / 4 waves

// k_out geometry: 100 blocks per g; wave owns contiguous 100-node span.
#define CHUNKO 400
#define NBO (N / CHUNKO)      // 100
#define WNODESO 100

typedef float v4f __attribute__((ext_vector_type(4)));

// Workspace layout (floats):
//   Spart : [G][NB][C][D] = 16*50*5*64 = 256000 floats @ 0
//   M2    : [G][C][D]     = 5120 floats               @ 256000
// All fully written before read -> poison-safe, no zero-init.

__global__ __launch_bounds__(256) void k_sums(const v4f* __restrict__ x,
                                              const int* __restrict__ lab,
                                              v4f* __restrict__ Spart) {
    const int g    = blockIdx.y;
    const int b    = blockIdx.x;
    const int tid  = threadIdx.x;
    const int w    = tid >> 6;       // wave 0..3
    const int lane = tid & 63;
    const int q    = lane & 15;      // dim-group (4 floats)
    const int rr   = lane >> 4;      // node sub-lane 0..3
    const int base = b * CHUNKS + w * WNODES;

    v4f acc[C];
#pragma unroll
    for (int c = 0; c < C; ++c) acc[c] = (v4f)0.f;

    const v4f* xg = x + (size_t)g * N * 16;
#pragma unroll 4
    for (int it = 0; it < WNODES / 4; ++it) {      // 50 iters, 4 nodes/wave-iter
        const int n   = base + it * 4 + rr;
        const int lbl = lab[n];
        v4f v = xg[(size_t)n * 16 + q];
#pragma unroll
        for (int c = 0; c < C; ++c)
            acc[c] += ((lbl == c) ? 1.f : 0.f) * v;
    }

    __shared__ v4f red[C][16][16];   // 20 KB
    const int row = w * 4 + rr;      // 0..15
#pragma unroll
    for (int c = 0; c < C; ++c) red[c][row][q] = acc[c];
    __syncthreads();

    const int qd = tid & 15;
    const int rd = tid >> 4;
    for (int s = 8; s >= 1; s >>= 1) {
        if (rd < s) {
#pragma unroll
            for (int c = 0; c < C; ++c)
                red[c][rd][qd] += red[c][rd + s][qd];
        }
        __syncthreads();
    }
    if (rd == 0) {
#pragma unroll
        for (int c = 0; c < C; ++c)
            Spart[(((size_t)g * NB + b) * C + c) * 16 + qd] = red[c][0][qd];
    }
}

// One block per (g, c): reduce partials + count class from lab, then
// M2 = relu(mean @ W1 + b1) @ W2 + b2
__global__ __launch_bounds__(256) void k_mlp(const float* __restrict__ Spart,
                                             const int* __restrict__ lab,
                                             const float* __restrict__ W1,
                                             const float* __restrict__ b1,
                                             const float* __restrict__ W2,
                                             const float* __restrict__ b2,
                                             float* __restrict__ M2) {
    const int gc  = blockIdx.x;   // g*C + c
    const int g   = gc / C;
    const int c   = gc % C;
    const int tid = threadIdx.x;
    const int d   = tid & 63;
    const int grp = tid >> 6;     // 0..3

    __shared__ float rs[4][D];
    __shared__ float xm[D];
    __shared__ float H[HID];
    __shared__ float pr[4][D];
    __shared__ int   wcnt[4];

    // partial-sum reduce: 4 thread-groups stride over the NB partials
    float s = 0.f;
    for (int bb = grp; bb < NB; bb += 4)
        s += Spart[(((size_t)g * NB + bb) * C + c) * D + d];
    rs[grp][d] = s;

    // class count: scan lab (160 KB, L2-hot), wave shuffle reduce
    int cnt = 0;
    for (int n = tid; n < N; n += 256) cnt += (lab[n] == c) ? 1 : 0;
#pragma unroll
    for (int off = 32; off >= 1; off >>= 1) cnt += __shfl_down(cnt, off);
    if ((tid & 63) == 0) wcnt[tid >> 6] = cnt;
    __syncthreads();

    if (tid < D) {
        float cc = (float)(wcnt[0] + wcnt[1] + wcnt[2] + wcnt[3]);
        if (cc < 1.f) cc = 1.f;
        xm[tid] = (rs[0][tid] + rs[1][tid] + rs[2][tid] + rs[3][tid]) / cc;
    }
    __syncthreads();

    float m1 = 0.f;
#pragma unroll
    for (int dd = 0; dd < D; ++dd) m1 = fmaf(xm[dd], W1[dd * HID + tid], m1);
    m1 += b1[tid];
    H[tid] = m1 > 0.f ? m1 : 0.f;
    __syncthreads();

    // second GEMV split across the 4 thread-groups (4x shorter chain)
    float p = 0.f;
    const int f0 = grp * 64;
#pragma unroll
    for (int ff = 0; ff < 64; ++ff)
        p = fmaf(H[f0 + ff], W2[(f0 + ff) * D + d], p);
    pr[grp][d] = p;
    __syncthreads();
    if (tid < D)
        M2[(size_t)gc * D + tid] =
            pr[0][tid] + pr[1][tid] + pr[2][tid] + pr[3][tid] + b2[tid];
}

__global__ __launch_bounds__(256) void k_out(const v4f* __restrict__ x,
                                             const int* __restrict__ lab,
                                             const v4f* __restrict__ M2,
                                             v4f* __restrict__ out) {
    const int g    = blockIdx.y;
    const int tid  = threadIdx.x;
    const int w    = tid >> 6;
    const int lane = tid & 63;
    const int q    = lane & 15;
    const int rr   = lane >> 4;
    const int base = blockIdx.x * CHUNKO + w * WNODESO;

    __shared__ v4f m2s[C][16];
    if (tid < C * 16) m2s[tid >> 4][tid & 15] = M2[(size_t)g * C * 16 + tid];
    __syncthreads();

    const size_t goff = (size_t)g * N * 16;
#pragma unroll 5
    for (int it = 0; it < WNODESO / 4; ++it) {     // 25 iters
        const int n   = base + it * 4 + rr;
        const int lbl = lab[n];
        v4f v = x[goff + (size_t)n * 16 + q];
        v += m2s[lbl][q];
        // nt store: keep x resident in L2/L3 for this pass's reads
        __builtin_nontemporal_store(v, out + goff + (size_t)n * 16 + q);
    }
}

extern "C" void kernel_launch(void* const* d_in, const int* in_sizes, int n_in,
                              void* d_out, int out_size, void* d_ws, size_t ws_size,
                              hipStream_t stream) {
    const float* x   = (const float*)d_in[0];
    const int*   lab = (const int*)d_in[1];
    const float* W1  = (const float*)d_in[2];
    const float* b1  = (const float*)d_in[3];
    const float* W2  = (const float*)d_in[4];
    const float* b2  = (const float*)d_in[5];
    float* out = (float*)d_out;

    float* wsf   = (float*)d_ws;
    float* Spart = wsf;              // 256000 floats
    float* M2    = wsf + 256000;     // 5120 floats

    dim3 gs(NB, G);
    k_sums<<<gs, 256, 0, stream>>>((const v4f*)x, lab, (v4f*)Spart);

    k_mlp<<<G * C, 256, 0, stream>>>(Spart, lab, W1, b1, W2, b2, M2);

    dim3 go(NBO, G);
    k_out<<<go, 256, 0, stream>>>((const v4f*)x, lab, (const v4f*)M2,
                                  (v4f*)out);
}